// Round 2
// baseline (2120.461 us; speedup 1.0000x reference)
//
#include <hip/hip_runtime.h>
#include <hip/hip_bf16.h>

// JKNet (6-layer GCN + jumping-knowledge concat) on MI355X.
// All tensors are fp32 (per reference); edge_index/percent are int32.
//
// d_in: 0:x[50000*96] f32, 1:edge_index[2*800000] i32, 2:percent i32 (unused),
//       3:ricci[800000] f32 (unused), 4:W1[96*96] f32, 5:b1[96] f32,
//       6:Ws[4*96*96] f32, 7:bs[4*96] f32, 8:Wout[480*64] f32, 9:bout[64] f32
// d_out (f32): out[50000*64] ++ h1..h5[50000*96 each].
// The h segments of d_out double as the forward activations (fp32).

// ---- degree / norm ---------------------------------------------------------
__global__ void deg_kernel(const int* __restrict__ dst, float* __restrict__ deg, int E) {
    int e = blockIdx.x * blockDim.x + threadIdx.x;
    if (e < E) atomicAdd(&deg[dst[e]], 1.0f);
}

__global__ void dinv_kernel(const float* __restrict__ deg, float* __restrict__ dinv, int n) {
    int v = blockIdx.x * blockDim.x + threadIdx.x;
    if (v < n) dinv[v] = rsqrtf(deg[v] + 1.0f);  // +1 = self loop; always > 0
}

// ---- GEMM [n,96] x [96,96] -> fp32 ----------------------------------------
// Block (96,4): W staged in LDS (36.9 KB), each thread computes one output elem.
__global__ void gemm96(const float* __restrict__ X, const float* __restrict__ W,
                       float* __restrict__ Y, int n) {
    __shared__ float Wl[96 * 96];
    __shared__ float Xl[4][96];
    const int tx = threadIdx.x;            // col 0..95
    const int ty = threadIdx.y;            // 0..3
    const int tid = ty * 96 + tx;
    for (int i = tid; i < 96 * 96; i += 384) Wl[i] = W[i];
    const int row = blockIdx.x * 4 + ty;
    if (row < n) Xl[ty][tx] = X[(size_t)row * 96 + tx];
    __syncthreads();
    if (row < n) {
        float acc = 0.f;
#pragma unroll
        for (int k = 0; k < 96; ++k) acc += Xl[ty][k] * Wl[k * 96 + tx];
        Y[(size_t)row * 96 + tx] = acc;
    }
}

// ---- final GEMM [n,480] x [480,64] -> fp32 ---------------------------------
// X is the JK concat: 5 segments of n*96 fp32 (h1..h5, living in d_out).
// K tiled in 5 chunks of 96. Block (64,4).
__global__ void gemm_out(const float* __restrict__ hcat,  // base of h1
                         const float* __restrict__ W,     // [480,64] row-major
                         float* __restrict__ Y, int n) {
    __shared__ float Wl[96 * 64];
    __shared__ float Xl[4][96];
    const int tx = threadIdx.x;  // col 0..63
    const int ty = threadIdx.y;  // 0..3
    const int tid = ty * 64 + tx;
    const int row = blockIdx.x * 4 + ty;
    float acc = 0.f;
    for (int l = 0; l < 5; ++l) {
        __syncthreads();  // protect previous tile's reads
        for (int i = tid; i < 96 * 64; i += 256) Wl[i] = W[l * 96 * 64 + i];
        const float* hl = hcat + (size_t)l * (size_t)n * 96;
        if (row < n) {
            Xl[ty][tx] = hl[(size_t)row * 96 + tx];
            if (tx < 32) Xl[ty][64 + tx] = hl[(size_t)row * 96 + 64 + tx];
        }
        __syncthreads();
        if (row < n) {
#pragma unroll
            for (int k = 0; k < 96; ++k) acc += Xl[ty][k] * Wl[k * 64 + tx];
        }
    }
    if (row < n) Y[(size_t)row * 64 + tx] = acc;
}

// ---- edge scatter-add: acc[dst] += h[src] * dinv[src]*dinv[dst] ------------
// 32 lanes per edge, 8 edges per 256-thread block; coalesced 128B atomic bursts.
__global__ void agg_edges(const int* __restrict__ src, const int* __restrict__ dst,
                          const float* __restrict__ dinv, const float* __restrict__ h,
                          float* __restrict__ acc, int E, int F) {
    const int lane = threadIdx.x & 31;
    const int e = blockIdx.x * 8 + (threadIdx.x >> 5);
    if (e >= E) return;
    const int s = src[e], d = dst[e];
    const float nrm = dinv[s] * dinv[d];
    const float* hs = h + (size_t)s * F;
    float* ad = acc + (size_t)d * F;
    for (int f = lane; f < F; f += 32) atomicAdd(&ad[f], hs[f] * nrm);
}

// ---- finalize hidden layer: self-loop + bias + ReLU -> fp32 (d_out segment)
__global__ void finalize_relu(const float* __restrict__ acc, const float* __restrict__ hg,
                              const float* __restrict__ dinv, const float* __restrict__ b,
                              float* __restrict__ hnext, int n) {
    int idx = blockIdx.x * blockDim.x + threadIdx.x;
    if (idx >= n * 96) return;
    int v = idx / 96, f = idx - v * 96;
    float di = dinv[v];
    float val = acc[idx] + hg[idx] * di * di + b[f];
    hnext[idx] = fmaxf(val, 0.f);
}

// ---- finalize output layer: self-loop + bias, no ReLU, F=64 ----------------
__global__ void finalize_out(const float* __restrict__ acc, const float* __restrict__ hg,
                             const float* __restrict__ dinv, const float* __restrict__ b,
                             float* __restrict__ out, int n) {
    int idx = blockIdx.x * blockDim.x + threadIdx.x;
    if (idx >= n * 64) return;
    int v = idx >> 6, f = idx & 63;
    float di = dinv[v];
    out[idx] = acc[idx] + hg[idx] * di * di + b[f];
}

extern "C" void kernel_launch(void* const* d_in, const int* in_sizes, int n_in,
                              void* d_out, int out_size, void* d_ws, size_t ws_size,
                              hipStream_t stream) {
    const float* x    = (const float*)d_in[0];
    const int*   ei   = (const int*)d_in[1];
    const float* W1   = (const float*)d_in[4];
    const float* b1   = (const float*)d_in[5];
    const float* Wsl  = (const float*)d_in[6];
    const float* bsl  = (const float*)d_in[7];
    const float* Wout = (const float*)d_in[8];
    const float* bout = (const float*)d_in[9];

    const int n = in_sizes[0] / 96;  // 50000
    const int E = in_sizes[1] / 2;   // 800000
    const int* src = ei;
    const int* dst = ei + E;

    // workspace (fp32): deg[n] | dinv[n] | bufB[n*96] (atomic acc) | bufC[n*96] (gemm out)
    float* deg  = (float*)d_ws;
    float* dinv = deg + n;
    float* bufB = dinv + n;
    float* bufC = bufB + (size_t)n * 96;

    float* out  = (float*)d_out;                 // [n,64]
    float* hseg = out + (size_t)n * 64;          // h1 base; 5 segments of n*96 fp32

    const int nthr = 256;
    const int gE   = (E + nthr - 1) / nthr;
    const int gN   = (n + nthr - 1) / nthr;
    const int gRow = (n + 3) / 4;
    const int gAgg = (E + 7) / 8;
    const int gF96 = (n * 96 + nthr - 1) / nthr;
    const int gF64 = (n * 64 + nthr - 1) / nthr;

    // degree + normalization (shared by all layers)
    hipMemsetAsync(deg, 0, (size_t)n * sizeof(float), stream);
    deg_kernel<<<gE, nthr, 0, stream>>>(dst, deg, E);
    dinv_kernel<<<gN, nthr, 0, stream>>>(deg, dinv, n);

    // layer 1: x -> h1
    gemm96<<<gRow, dim3(96, 4), 0, stream>>>(x, W1, bufC, n);
    hipMemsetAsync(bufB, 0, (size_t)n * 96 * sizeof(float), stream);
    agg_edges<<<gAgg, nthr, 0, stream>>>(src, dst, dinv, bufC, bufB, E, 96);
    finalize_relu<<<gF96, nthr, 0, stream>>>(bufB, bufC, dinv, b1, hseg, n);

    // hidden layers 2..5: h_{l} -> h_{l+1}
    for (int l = 0; l < 4; ++l) {
        const float* hin = hseg + (size_t)l * (size_t)n * 96;
        float* hnext     = hseg + (size_t)(l + 1) * (size_t)n * 96;
        gemm96<<<gRow, dim3(96, 4), 0, stream>>>(hin, Wsl + (size_t)l * 96 * 96, bufC, n);
        hipMemsetAsync(bufB, 0, (size_t)n * 96 * sizeof(float), stream);
        agg_edges<<<gAgg, nthr, 0, stream>>>(src, dst, dinv, bufC, bufB, E, 96);
        finalize_relu<<<gF96, nthr, 0, stream>>>(bufB, bufC, dinv, bsl + (size_t)l * 96, hnext, n);
    }

    // output layer: JK concat (h1..h5 in d_out) -> out[n,64]
    gemm_out<<<gRow, dim3(64, 4), 0, stream>>>(hseg, Wout, bufC, n);
    hipMemsetAsync(bufB, 0, (size_t)n * 64 * sizeof(float), stream);
    agg_edges<<<gAgg, nthr, 0, stream>>>(src, dst, dinv, bufC, bufB, E, 64);
    finalize_out<<<gF64, nthr, 0, stream>>>(bufB, bufC, dinv, bout, out, n);
}

// Round 3
// 1311.090 us; speedup vs baseline: 1.6173x; 1.6173x over previous
//
#include <hip/hip_runtime.h>

// JKNet (6-layer GCN + JK concat) on MI355X — R3: atomic scatter -> CSR gather.
//
// d_in: 0:x[50000*96] f32, 1:edge_index[2*800000] i32, 2:percent i32 (unused),
//       3:ricci[800000] f32 (unused), 4:W1[96*96] f32, 5:b1[96] f32,
//       6:Ws[4*96*96] f32, 7:bs[4*96] f32, 8:Wout[480*64] f32, 9:bout[64] f32
// d_out (f32): out[50000*64] ++ h1..h5[50000*96 each]; h segments double as activations.
//
// Per layer: g = (X@W) * dinv[row]  (GEMM epilogue fold), then
//            h_next[v] = act((sum_{s in N_in(v)} g[s] + g[v]) * dinv[v] + b)
// CSR (in-edges grouped by dst) built once per call; no fp32 atomics anywhere.

// ---- CSR build -------------------------------------------------------------
__global__ void count_kernel(const int* __restrict__ dst, int* __restrict__ degi, int E) {
    int e = blockIdx.x * blockDim.x + threadIdx.x;
    if (e < E) atomicAdd(&degi[dst[e]], 1);
}

// Single-block exclusive scan over n degree counts; also emits dinv = rsqrt(deg+1).
__global__ void scan_kernel(const int* __restrict__ degi, int* __restrict__ row_start,
                            float* __restrict__ dinv, int n) {
    __shared__ int part[1024];
    const int t = threadIdx.x;
    const int chunk = (n + 1023) >> 10;
    const int lo = t * chunk;
    const int hi = min(n, lo + chunk);
    int s = 0;
    for (int i = lo; i < hi; ++i) s += degi[i];
    part[t] = s;
    __syncthreads();
    for (int off = 1; off < 1024; off <<= 1) {   // Hillis-Steele inclusive scan
        int v = (t >= off) ? part[t - off] : 0;
        __syncthreads();
        part[t] += v;
        __syncthreads();
    }
    int run = (t > 0) ? part[t - 1] : 0;         // exclusive prefix at chunk start
    for (int i = lo; i < hi; ++i) {
        int d = degi[i];
        row_start[i] = run;
        run += d;
        dinv[i] = rsqrtf((float)d + 1.0f);       // +1 self loop; always > 0
    }
    if (t == 1023) row_start[n] = run;           // total E (empty tail chunk => run = total)
}

__global__ void fill_kernel(const int* __restrict__ src, const int* __restrict__ dst,
                            const int* __restrict__ row_start, int* __restrict__ cnt,
                            int* __restrict__ col, int E) {
    int e = blockIdx.x * blockDim.x + threadIdx.x;
    if (e < E) {
        int d = dst[e];
        int pos = row_start[d] + atomicAdd(&cnt[d], 1);
        col[pos] = src[e];
    }
}

// ---- GEMM [n,96] x [96,96] -> g = Y * dinv[row] ---------------------------
// Block (96,4): W staged in LDS, one output element per thread.
__global__ void gemm96(const float* __restrict__ X, const float* __restrict__ W,
                       const float* __restrict__ dinv, float* __restrict__ g, int n) {
    __shared__ float Wl[96 * 96];
    __shared__ float Xl[4][96];
    const int tx = threadIdx.x;            // col 0..95
    const int ty = threadIdx.y;            // 0..3
    const int tid = ty * 96 + tx;
    for (int i = tid; i < 96 * 96; i += 384) Wl[i] = W[i];
    const int row = blockIdx.x * 4 + ty;
    if (row < n) Xl[ty][tx] = X[(size_t)row * 96 + tx];
    __syncthreads();
    if (row < n) {
        float acc = 0.f;
#pragma unroll
        for (int k = 0; k < 96; ++k) acc += Xl[ty][k] * Wl[k * 96 + tx];
        g[(size_t)row * 96 + tx] = acc * dinv[row];
    }
}

// ---- final GEMM [n,480] x [480,64] -> g64 = Y * dinv[row] ------------------
// X = JK concat: 5 segments of n*96 fp32 (h1..h5, in d_out). Block (64,4).
__global__ void gemm_out(const float* __restrict__ hcat, const float* __restrict__ W,
                         const float* __restrict__ dinv, float* __restrict__ g, int n) {
    __shared__ float Wl[96 * 64];
    __shared__ float Xl[4][96];
    const int tx = threadIdx.x;  // col 0..63
    const int ty = threadIdx.y;  // 0..3
    const int tid = ty * 64 + tx;
    const int row = blockIdx.x * 4 + ty;
    float acc = 0.f;
    for (int l = 0; l < 5; ++l) {
        __syncthreads();  // protect previous tile's reads
        for (int i = tid; i < 96 * 64; i += 256) Wl[i] = W[l * 96 * 64 + i];
        const float* hl = hcat + (size_t)l * (size_t)n * 96;
        if (row < n) {
            Xl[ty][tx] = hl[(size_t)row * 96 + tx];
            if (tx < 32) Xl[ty][64 + tx] = hl[(size_t)row * 96 + 64 + tx];
        }
        __syncthreads();
        if (row < n) {
#pragma unroll
            for (int k = 0; k < 96; ++k) acc += Xl[ty][k] * Wl[k * 64 + tx];
        }
    }
    if (row < n) g[(size_t)row * 64 + tx] = acc * dinv[row];
}

// ---- CSR gather-aggregate + fused epilogue ---------------------------------
// One wave (64 lanes) per node. F=96: lane covers f=lane, lanes<32 also f=64+lane.
template <int F, bool RELU>
__global__ void agg_csr(const int* __restrict__ row_start, const int* __restrict__ col,
                        const float* __restrict__ g, const float* __restrict__ dinv,
                        const float* __restrict__ b, float* __restrict__ out, int n) {
    const int lane = threadIdx.x & 63;
    const int v = blockIdx.x * (blockDim.x >> 6) + (threadIdx.x >> 6);
    if (v >= n) return;
    const int e0 = row_start[v];
    const int e1 = row_start[v + 1];
    float acc0 = g[(size_t)v * F + lane];                       // self loop
    float acc1 = (F == 96 && lane < 32) ? g[(size_t)v * F + 64 + lane] : 0.f;
    for (int e = e0; e < e1; ++e) {
        const float* gr = g + (size_t)col[e] * F;
        acc0 += gr[lane];
        if (F == 96 && lane < 32) acc1 += gr[64 + lane];
    }
    const float di = dinv[v];
    float r0 = acc0 * di + b[lane];
    if (RELU) r0 = fmaxf(r0, 0.f);
    out[(size_t)v * F + lane] = r0;
    if (F == 96 && lane < 32) {
        float r1 = acc1 * di + b[64 + lane];
        if (RELU) r1 = fmaxf(r1, 0.f);
        out[(size_t)v * F + 64 + lane] = r1;
    }
}

extern "C" void kernel_launch(void* const* d_in, const int* in_sizes, int n_in,
                              void* d_out, int out_size, void* d_ws, size_t ws_size,
                              hipStream_t stream) {
    const float* x    = (const float*)d_in[0];
    const int*   ei   = (const int*)d_in[1];
    const float* W1   = (const float*)d_in[4];
    const float* b1   = (const float*)d_in[5];
    const float* Wsl  = (const float*)d_in[6];
    const float* bsl  = (const float*)d_in[7];
    const float* Wout = (const float*)d_in[8];
    const float* bout = (const float*)d_in[9];

    const int n = in_sizes[0] / 96;  // 50000
    const int E = in_sizes[1] / 2;   // 800000
    const int* src = ei;
    const int* dst = ei + E;

    // workspace: degi[n] | row_start[n+1] | cnt[n] | col[E] (ints), dinv[n] | g[n*96] (f32)
    int*   degi      = (int*)d_ws;
    int*   row_start = degi + n;
    int*   cnt       = row_start + n + 1;
    int*   col       = cnt + n;
    float* dinv      = (float*)(col + E);
    float* g         = dinv + n;

    float* out  = (float*)d_out;          // [n,64]
    float* hseg = out + (size_t)n * 64;   // h1 base; 5 segments of n*96 fp32

    const int nthr = 256;
    const int gE   = (E + nthr - 1) / nthr;
    const int gAgg = (n + 3) / 4;         // 4 waves/block, 1 node/wave
    const int gRow = (n + 3) / 4;

    // ---- CSR build (per call; graph-capture-safe, same work every call) ----
    hipMemsetAsync(degi, 0, (size_t)n * sizeof(int), stream);
    count_kernel<<<gE, nthr, 0, stream>>>(dst, degi, E);
    scan_kernel<<<1, 1024, 0, stream>>>(degi, row_start, dinv, n);
    hipMemsetAsync(cnt, 0, (size_t)n * sizeof(int), stream);
    fill_kernel<<<gE, nthr, 0, stream>>>(src, dst, row_start, cnt, col, E);

    // ---- layer 1: x -> h1 ----
    gemm96<<<gRow, dim3(96, 4), 0, stream>>>(x, W1, dinv, g, n);
    agg_csr<96, true><<<gAgg, nthr, 0, stream>>>(row_start, col, g, dinv, b1, hseg, n);

    // ---- hidden layers 2..5 ----
    for (int l = 0; l < 4; ++l) {
        const float* hin = hseg + (size_t)l * (size_t)n * 96;
        float* hnext     = hseg + (size_t)(l + 1) * (size_t)n * 96;
        gemm96<<<gRow, dim3(96, 4), 0, stream>>>(hin, Wsl + (size_t)l * 96 * 96, dinv, g, n);
        agg_csr<96, true><<<gAgg, nthr, 0, stream>>>(row_start, col, g, dinv,
                                                     bsl + (size_t)l * 96, hnext, n);
    }

    // ---- output layer: JK concat -> out[n,64] ----
    gemm_out<<<gRow, dim3(64, 4), 0, stream>>>(hseg, Wout, dinv, g, n);
    agg_csr<64, false><<<gAgg, nthr, 0, stream>>>(row_start, col, g, dinv, bout, out, n);
}

// Round 4
// 895.311 us; speedup vs baseline: 2.3684x; 1.4644x over previous
//
#include <hip/hip_runtime.h>

// JKNet (6-layer GCN + JK concat) on MI355X — R4: register-tiled GEMMs (8x8/thread),
// float4+unroll-4 CSR gather. CSR build + dinv once per call; no fp32 atomics.
//
// d_in: 0:x[50000*96] f32, 1:edge_index[2*800000] i32, 2:percent i32, 3:ricci f32,
//       4:W1[96*96], 5:b1[96], 6:Ws[4*96*96], 7:bs[4*96], 8:Wout[480*64], 9:bout[64]
// d_out (f32): out[50000*64] ++ h1..h5[50000*96]; h segments double as activations.
// Per layer: g = (X@W)*dinv[row], then h[v] = act((sum_{s in N(v)} g[s] + g[v])*dinv[v] + b).

// ---- CSR build -------------------------------------------------------------
__global__ void count_kernel(const int* __restrict__ dst, int* __restrict__ degi, int E) {
    int e = blockIdx.x * blockDim.x + threadIdx.x;
    if (e < E) atomicAdd(&degi[dst[e]], 1);
}

__global__ void scan_kernel(const int* __restrict__ degi, int* __restrict__ row_start,
                            float* __restrict__ dinv, int n) {
    __shared__ int part[1024];
    const int t = threadIdx.x;
    const int chunk = (n + 1023) >> 10;
    const int lo = t * chunk;
    const int hi = min(n, lo + chunk);
    int s = 0;
    for (int i = lo; i < hi; ++i) s += degi[i];
    part[t] = s;
    __syncthreads();
    for (int off = 1; off < 1024; off <<= 1) {
        int v = (t >= off) ? part[t - off] : 0;
        __syncthreads();
        part[t] += v;
        __syncthreads();
    }
    int run = (t > 0) ? part[t - 1] : 0;
    for (int i = lo; i < hi; ++i) {
        int d = degi[i];
        row_start[i] = run;
        run += d;
        dinv[i] = rsqrtf((float)d + 1.0f);
    }
    if (t == 1023) row_start[n] = run;
}

__global__ void fill_kernel(const int* __restrict__ src, const int* __restrict__ dst,
                            const int* __restrict__ row_start, int* __restrict__ cnt,
                            int* __restrict__ col, int E) {
    int e = blockIdx.x * blockDim.x + threadIdx.x;
    if (e < E) {
        int d = dst[e];
        int pos = row_start[d] + atomicAdd(&cnt[d], 1);
        col[pos] = src[e];
    }
}

// ---- GEMM [n,96]x[96,96] -> g = Y*dinv[row]. Tile 128x96, 192 thr, 8x8/thread.
__global__ __launch_bounds__(192) void gemm96_rt(const float* __restrict__ X,
                                                 const float* __restrict__ W,
                                                 const float* __restrict__ dinv,
                                                 float* __restrict__ g, int n) {
    __shared__ float Wl[96 * 96];     // [k][c]
    __shared__ float Xl[32][128];     // [kk][row]  (transposed slab)
    const int tid = threadIdx.x;
    const int cg = tid % 12;          // 12 col groups x 8 cols
    const int rg = tid / 12;          // 16 row groups x 8 rows
    const int row_base = blockIdx.x * 128;
    for (int i = tid * 4; i < 96 * 96; i += 192 * 4)
        *(float4*)&Wl[i] = *(const float4*)&W[i];
    float acc[8][8] = {};
    for (int s = 0; s < 3; ++s) {
        __syncthreads();  // protect previous slab reads
        for (int i = tid; i < 1024; i += 192) {   // 128 rows x 32 k as float4
            int r = i >> 3, kg = i & 7;
            int grow = min(row_base + r, n - 1);
            float4 vx = *(const float4*)&X[(size_t)grow * 96 + s * 32 + kg * 4];
            Xl[kg * 4 + 0][r] = vx.x;
            Xl[kg * 4 + 1][r] = vx.y;
            Xl[kg * 4 + 2][r] = vx.z;
            Xl[kg * 4 + 3][r] = vx.w;
        }
        __syncthreads();
#pragma unroll
        for (int kk = 0; kk < 32; ++kk) {
            const int k = s * 32 + kk;
            float4 a0 = *(float4*)&Xl[kk][rg * 8];
            float4 a1 = *(float4*)&Xl[kk][rg * 8 + 4];
            float4 b0 = *(float4*)&Wl[k * 96 + cg * 8];
            float4 b1 = *(float4*)&Wl[k * 96 + cg * 8 + 4];
            const float av[8] = {a0.x, a0.y, a0.z, a0.w, a1.x, a1.y, a1.z, a1.w};
            const float bv[8] = {b0.x, b0.y, b0.z, b0.w, b1.x, b1.y, b1.z, b1.w};
#pragma unroll
            for (int i = 0; i < 8; ++i)
#pragma unroll
                for (int j = 0; j < 8; ++j) acc[i][j] += av[i] * bv[j];
        }
    }
    const int c0 = cg * 8;
#pragma unroll
    for (int i = 0; i < 8; ++i) {
        int row = row_base + rg * 8 + i;
        if (row < n) {
            float di = dinv[row];
            float4 r0 = {acc[i][0] * di, acc[i][1] * di, acc[i][2] * di, acc[i][3] * di};
            float4 r1 = {acc[i][4] * di, acc[i][5] * di, acc[i][6] * di, acc[i][7] * di};
            *(float4*)&g[(size_t)row * 96 + c0] = r0;
            *(float4*)&g[(size_t)row * 96 + c0 + 4] = r1;
        }
    }
}

// ---- GEMM [n,480]x[480,64] -> g = Y*dinv[row]. Tile 128x64, 128 thr, 8x8/thread.
// X = JK concat (5 segments of n*96); K slab 32 never crosses a segment (96 = 3*32).
__global__ __launch_bounds__(128) void gemm_out_rt(const float* __restrict__ hcat,
                                                   const float* __restrict__ W,
                                                   const float* __restrict__ dinv,
                                                   float* __restrict__ g, int n) {
    __shared__ float Wl[32 * 64];     // [kk][c]
    __shared__ float Xl[32][128];     // [kk][row]
    const int tid = threadIdx.x;
    const int cg = tid & 7;           // 8 col groups x 8 cols
    const int rg = tid >> 3;          // 16 row groups x 8 rows
    const int row_base = blockIdx.x * 128;
    float acc[8][8] = {};
    for (int s = 0; s < 15; ++s) {
        const float* hl = hcat + (size_t)(s / 3) * (size_t)n * 96;
        const int off = (s % 3) * 32;
        __syncthreads();
        for (int i = tid * 4; i < 32 * 64; i += 128 * 4)
            *(float4*)&Wl[i] = *(const float4*)&W[s * 32 * 64 + i];
        for (int i = tid; i < 1024; i += 128) {
            int r = i >> 3, kg = i & 7;
            int grow = min(row_base + r, n - 1);
            float4 vx = *(const float4*)&hl[(size_t)grow * 96 + off + kg * 4];
            Xl[kg * 4 + 0][r] = vx.x;
            Xl[kg * 4 + 1][r] = vx.y;
            Xl[kg * 4 + 2][r] = vx.z;
            Xl[kg * 4 + 3][r] = vx.w;
        }
        __syncthreads();
#pragma unroll
        for (int kk = 0; kk < 32; ++kk) {
            float4 a0 = *(float4*)&Xl[kk][rg * 8];
            float4 a1 = *(float4*)&Xl[kk][rg * 8 + 4];
            float4 b0 = *(float4*)&Wl[kk * 64 + cg * 8];
            float4 b1 = *(float4*)&Wl[kk * 64 + cg * 8 + 4];
            const float av[8] = {a0.x, a0.y, a0.z, a0.w, a1.x, a1.y, a1.z, a1.w};
            const float bv[8] = {b0.x, b0.y, b0.z, b0.w, b1.x, b1.y, b1.z, b1.w};
#pragma unroll
            for (int i = 0; i < 8; ++i)
#pragma unroll
                for (int j = 0; j < 8; ++j) acc[i][j] += av[i] * bv[j];
        }
    }
    const int c0 = cg * 8;
#pragma unroll
    for (int i = 0; i < 8; ++i) {
        int row = row_base + rg * 8 + i;
        if (row < n) {
            float di = dinv[row];
            float4 r0 = {acc[i][0] * di, acc[i][1] * di, acc[i][2] * di, acc[i][3] * di};
            float4 r1 = {acc[i][4] * di, acc[i][5] * di, acc[i][6] * di, acc[i][7] * di};
            *(float4*)&g[(size_t)row * 64 + c0] = r0;
            *(float4*)&g[(size_t)row * 64 + c0 + 4] = r1;
        }
    }
}

// ---- CSR gather-aggregate + fused epilogue ---------------------------------
// One wave per node; lanes 0..F/4-1 hold float4 features. 4-edge unroll.
template <int F, bool RELU>
__global__ void agg_csr(const int* __restrict__ row_start, const int* __restrict__ col,
                        const float* __restrict__ g, const float* __restrict__ dinv,
                        const float* __restrict__ b, float* __restrict__ out, int n) {
    constexpr int NV = F / 4;
    const int lane = threadIdx.x & 63;
    const int v = blockIdx.x * (blockDim.x >> 6) + (threadIdx.x >> 6);
    if (v >= n) return;
    const int e0 = row_start[v];
    const int e1 = row_start[v + 1];
    float4 acc = {0.f, 0.f, 0.f, 0.f};
    if (lane < NV) acc = *(const float4*)&g[(size_t)v * F + lane * 4];  // self loop
    int e = e0;
    for (; e + 3 < e1; e += 4) {
        int c0 = col[e], c1 = col[e + 1], c2 = col[e + 2], c3 = col[e + 3];
        if (lane < NV) {
            float4 g0 = *(const float4*)&g[(size_t)c0 * F + lane * 4];
            float4 g1 = *(const float4*)&g[(size_t)c1 * F + lane * 4];
            float4 g2 = *(const float4*)&g[(size_t)c2 * F + lane * 4];
            float4 g3 = *(const float4*)&g[(size_t)c3 * F + lane * 4];
            acc.x += g0.x; acc.y += g0.y; acc.z += g0.z; acc.w += g0.w;
            acc.x += g1.x; acc.y += g1.y; acc.z += g1.z; acc.w += g1.w;
            acc.x += g2.x; acc.y += g2.y; acc.z += g2.z; acc.w += g2.w;
            acc.x += g3.x; acc.y += g3.y; acc.z += g3.z; acc.w += g3.w;
        }
    }
    for (; e < e1; ++e) {
        int c = col[e];
        if (lane < NV) {
            float4 g0 = *(const float4*)&g[(size_t)c * F + lane * 4];
            acc.x += g0.x; acc.y += g0.y; acc.z += g0.z; acc.w += g0.w;
        }
    }
    if (lane < NV) {
        const float di = dinv[v];
        float4 r;
        r.x = acc.x * di + b[lane * 4 + 0];
        r.y = acc.y * di + b[lane * 4 + 1];
        r.z = acc.z * di + b[lane * 4 + 2];
        r.w = acc.w * di + b[lane * 4 + 3];
        if (RELU) {
            r.x = fmaxf(r.x, 0.f); r.y = fmaxf(r.y, 0.f);
            r.z = fmaxf(r.z, 0.f); r.w = fmaxf(r.w, 0.f);
        }
        *(float4*)&out[(size_t)v * F + lane * 4] = r;
    }
}

extern "C" void kernel_launch(void* const* d_in, const int* in_sizes, int n_in,
                              void* d_out, int out_size, void* d_ws, size_t ws_size,
                              hipStream_t stream) {
    const float* x    = (const float*)d_in[0];
    const int*   ei   = (const int*)d_in[1];
    const float* W1   = (const float*)d_in[4];
    const float* b1   = (const float*)d_in[5];
    const float* Wsl  = (const float*)d_in[6];
    const float* bsl  = (const float*)d_in[7];
    const float* Wout = (const float*)d_in[8];
    const float* bout = (const float*)d_in[9];

    const int n = in_sizes[0] / 96;  // 50000
    const int E = in_sizes[1] / 2;   // 800000
    const int* src = ei;
    const int* dst = ei + E;

    int*   degi      = (int*)d_ws;
    int*   row_start = degi + n;
    int*   cnt       = row_start + n + 1;
    int*   col       = cnt + n;
    float* dinv      = (float*)(col + E);
    float* g         = dinv + n;

    float* out  = (float*)d_out;          // [n,64]
    float* hseg = out + (size_t)n * 64;   // h1 base; 5 segments of n*96

    const int nthr = 256;
    const int gE   = (E + nthr - 1) / nthr;
    const int gAgg = (n + 3) / 4;         // 4 waves/block, 1 node/wave
    const int gTile = (n + 127) / 128;

    // CSR build (same work every call; graph-capture-safe)
    hipMemsetAsync(degi, 0, (size_t)n * sizeof(int), stream);
    count_kernel<<<gE, nthr, 0, stream>>>(dst, degi, E);
    scan_kernel<<<1, 1024, 0, stream>>>(degi, row_start, dinv, n);
    hipMemsetAsync(cnt, 0, (size_t)n * sizeof(int), stream);
    fill_kernel<<<gE, nthr, 0, stream>>>(src, dst, row_start, cnt, col, E);

    // layer 1
    gemm96_rt<<<gTile, 192, 0, stream>>>(x, W1, dinv, g, n);
    agg_csr<96, true><<<gAgg, nthr, 0, stream>>>(row_start, col, g, dinv, b1, hseg, n);

    // hidden layers 2..5
    for (int l = 0; l < 4; ++l) {
        const float* hin = hseg + (size_t)l * (size_t)n * 96;
        float* hnext     = hseg + (size_t)(l + 1) * (size_t)n * 96;
        gemm96_rt<<<gTile, 192, 0, stream>>>(hin, Wsl + (size_t)l * 96 * 96, dinv, g, n);
        agg_csr<96, true><<<gAgg, nthr, 0, stream>>>(row_start, col, g, dinv,
                                                     bsl + (size_t)l * 96, hnext, n);
    }

    // output layer
    gemm_out_rt<<<gTile, 128, 0, stream>>>(hseg, Wout, dinv, g, n);
    agg_csr<64, false><<<gAgg, nthr, 0, stream>>>(row_start, col, g, dinv, bout, out, n);
}

// Round 5
// 787.456 us; speedup vs baseline: 2.6928x; 1.1370x over previous
//
#include <hip/hip_runtime.h>

// JKNet (6-layer GCN + JK concat) on MI355X — R5:
//   * GEMMs re-tiled to 4x4/thread (fix R4's 8% occupancy: 0.76 -> 3-4.6 waves/SIMD)
//   * g stored as bf16 -> aggregation gather traffic halves (3 lines/edge vs 6)
// Per layer: g = bf16((X@W)*dinv[row]); h[v] = act((sum_{N(v)} g[s] + g[v])*dinv[v] + b).
// CSR build + dinv once per call; no fp32 atomics.

typedef unsigned short ushortT;

__device__ __forceinline__ ushortT f2b(float f) {
    union { float f; unsigned int u; } v;
    v.f = f;
    // round-to-nearest-even bf16
    unsigned int lsb = (v.u >> 16) & 1u;
    v.u += 0x7fffu + lsb;
    return (ushortT)(v.u >> 16);
}
__device__ __forceinline__ float b2f(ushortT u) {
    union { float f; unsigned int u; } v;
    v.u = ((unsigned int)u) << 16;
    return v.f;
}

// ---- CSR build -------------------------------------------------------------
__global__ void count_kernel(const int* __restrict__ dst, int* __restrict__ degi, int E) {
    int e = blockIdx.x * blockDim.x + threadIdx.x;
    if (e < E) atomicAdd(&degi[dst[e]], 1);
}

__global__ void scan_kernel(const int* __restrict__ degi, int* __restrict__ row_start,
                            float* __restrict__ dinv, int n) {
    __shared__ int part[1024];
    const int t = threadIdx.x;
    const int chunk = (n + 1023) >> 10;
    const int lo = t * chunk;
    const int hi = min(n, lo + chunk);
    int s = 0;
    for (int i = lo; i < hi; ++i) s += degi[i];
    part[t] = s;
    __syncthreads();
    for (int off = 1; off < 1024; off <<= 1) {
        int v = (t >= off) ? part[t - off] : 0;
        __syncthreads();
        part[t] += v;
        __syncthreads();
    }
    int run = (t > 0) ? part[t - 1] : 0;
    for (int i = lo; i < hi; ++i) {
        int d = degi[i];
        row_start[i] = run;
        run += d;
        dinv[i] = rsqrtf((float)d + 1.0f);
    }
    if (t == 1023) row_start[n] = run;
}

__global__ void fill_kernel(const int* __restrict__ src, const int* __restrict__ dst,
                            const int* __restrict__ row_start, int* __restrict__ cnt,
                            int* __restrict__ col, int E) {
    int e = blockIdx.x * blockDim.x + threadIdx.x;
    if (e < E) {
        int d = dst[e];
        int pos = row_start[d] + atomicAdd(&cnt[d], 1);
        col[pos] = src[e];
    }
}

// ---- GEMM [n,96]x[96,96] -> g(bf16) = (X@W)*dinv[row]. Tile 64x96, 384 thr, 4x4/thr.
__global__ __launch_bounds__(384) void gemm96_v2(const float* __restrict__ X,
                                                 const float* __restrict__ W,
                                                 const float* __restrict__ dinv,
                                                 ushortT* __restrict__ g, int n) {
    __shared__ float Wl[96 * 96];     // [k][c]
    __shared__ float Xl[32][64];      // [kk][row] transposed slab
    const int tid = threadIdx.x;
    const int cg = tid % 24;          // 24 col groups x 4
    const int rg = tid / 24;          // 16 row groups x 4
    const int row_base = blockIdx.x * 64;
    for (int i = tid * 4; i < 96 * 96; i += 384 * 4)
        *(float4*)&Wl[i] = *(const float4*)&W[i];
    float acc[4][4] = {};
    for (int s = 0; s < 3; ++s) {
        __syncthreads();
        for (int i = tid; i < 512; i += 384) {         // 64 rows x 8 float4
            int r = i >> 3, kg = i & 7;
            int grow = min(row_base + r, n - 1);
            float4 vx = *(const float4*)&X[(size_t)grow * 96 + s * 32 + kg * 4];
            Xl[kg * 4 + 0][r] = vx.x;
            Xl[kg * 4 + 1][r] = vx.y;
            Xl[kg * 4 + 2][r] = vx.z;
            Xl[kg * 4 + 3][r] = vx.w;
        }
        __syncthreads();
#pragma unroll
        for (int kk = 0; kk < 32; ++kk) {
            float4 a = *(float4*)&Xl[kk][rg * 4];
            float4 b = *(float4*)&Wl[(s * 32 + kk) * 96 + cg * 4];
            const float av[4] = {a.x, a.y, a.z, a.w};
            const float bv[4] = {b.x, b.y, b.z, b.w};
#pragma unroll
            for (int i = 0; i < 4; ++i)
#pragma unroll
                for (int j = 0; j < 4; ++j) acc[i][j] += av[i] * bv[j];
        }
    }
#pragma unroll
    for (int i = 0; i < 4; ++i) {
        int row = row_base + rg * 4 + i;
        if (row < n) {
            float di = dinv[row];
            ushort4 o;
            o.x = f2b(acc[i][0] * di);
            o.y = f2b(acc[i][1] * di);
            o.z = f2b(acc[i][2] * di);
            o.w = f2b(acc[i][3] * di);
            *(ushort4*)&g[(size_t)row * 96 + cg * 4] = o;
        }
    }
}

// ---- GEMM [n,480]x[480,64] -> g(bf16). Tile 64x64, 256 thr, 4x4/thr, K=15 slabs of 32.
__global__ __launch_bounds__(256) void gemm_out_v2(const float* __restrict__ hcat,
                                                   const float* __restrict__ W,
                                                   const float* __restrict__ dinv,
                                                   ushortT* __restrict__ g, int n) {
    __shared__ float Wl[32 * 64];     // [kk][c]
    __shared__ float Xl[32][64];      // [kk][row]
    const int tid = threadIdx.x;
    const int cg = tid & 15;          // 16 col groups x 4
    const int rg = tid >> 4;          // 16 row groups x 4
    const int row_base = blockIdx.x * 64;
    float acc[4][4] = {};
    for (int s = 0; s < 15; ++s) {
        const float* hl = hcat + (size_t)(s / 3) * (size_t)n * 96;
        const int off = (s % 3) * 32;
        __syncthreads();
        for (int i = tid * 4; i < 32 * 64; i += 256 * 4)
            *(float4*)&Wl[i] = *(const float4*)&W[s * 32 * 64 + i];
        for (int i = tid; i < 512; i += 256) {
            int r = i >> 3, kg = i & 7;
            int grow = min(row_base + r, n - 1);
            float4 vx = *(const float4*)&hl[(size_t)grow * 96 + off + kg * 4];
            Xl[kg * 4 + 0][r] = vx.x;
            Xl[kg * 4 + 1][r] = vx.y;
            Xl[kg * 4 + 2][r] = vx.z;
            Xl[kg * 4 + 3][r] = vx.w;
        }
        __syncthreads();
#pragma unroll
        for (int kk = 0; kk < 32; ++kk) {
            float4 a = *(float4*)&Xl[kk][rg * 4];
            float4 b = *(float4*)&Wl[kk * 64 + cg * 4];
            const float av[4] = {a.x, a.y, a.z, a.w};
            const float bv[4] = {b.x, b.y, b.z, b.w};
#pragma unroll
            for (int i = 0; i < 4; ++i)
#pragma unroll
                for (int j = 0; j < 4; ++j) acc[i][j] += av[i] * bv[j];
        }
    }
#pragma unroll
    for (int i = 0; i < 4; ++i) {
        int row = row_base + rg * 4 + i;
        if (row < n) {
            float di = dinv[row];
            ushort4 o;
            o.x = f2b(acc[i][0] * di);
            o.y = f2b(acc[i][1] * di);
            o.z = f2b(acc[i][2] * di);
            o.w = f2b(acc[i][3] * di);
            *(ushort4*)&g[(size_t)row * 64 + cg * 4] = o;
        }
    }
}

// ---- CSR gather-aggregate (bf16 g) + fused epilogue (fp32 h out) -----------
// One wave per node; lanes 0..F/4-1 hold 4 features (ushort4 = 8B loads).
template <int F, bool RELU>
__global__ void agg_csr(const int* __restrict__ row_start, const int* __restrict__ col,
                        const ushortT* __restrict__ g, const float* __restrict__ dinv,
                        const float* __restrict__ b, float* __restrict__ out, int n) {
    constexpr int NV = F / 4;
    const int lane = threadIdx.x & 63;
    const int v = blockIdx.x * (blockDim.x >> 6) + (threadIdx.x >> 6);
    if (v >= n) return;
    const int e0 = row_start[v];
    const int e1 = row_start[v + 1];
    float a0 = 0.f, a1 = 0.f, a2 = 0.f, a3 = 0.f;
    if (lane < NV) {
        ushort4 s = *(const ushort4*)&g[(size_t)v * F + lane * 4];  // self loop
        a0 = b2f(s.x); a1 = b2f(s.y); a2 = b2f(s.z); a3 = b2f(s.w);
    }
    int e = e0;
    for (; e + 3 < e1; e += 4) {
        int c0 = col[e], c1 = col[e + 1], c2 = col[e + 2], c3 = col[e + 3];
        if (lane < NV) {
            ushort4 g0 = *(const ushort4*)&g[(size_t)c0 * F + lane * 4];
            ushort4 g1 = *(const ushort4*)&g[(size_t)c1 * F + lane * 4];
            ushort4 g2 = *(const ushort4*)&g[(size_t)c2 * F + lane * 4];
            ushort4 g3 = *(const ushort4*)&g[(size_t)c3 * F + lane * 4];
            a0 += b2f(g0.x) + b2f(g1.x) + b2f(g2.x) + b2f(g3.x);
            a1 += b2f(g0.y) + b2f(g1.y) + b2f(g2.y) + b2f(g3.y);
            a2 += b2f(g0.z) + b2f(g1.z) + b2f(g2.z) + b2f(g3.z);
            a3 += b2f(g0.w) + b2f(g1.w) + b2f(g2.w) + b2f(g3.w);
        }
    }
    for (; e < e1; ++e) {
        int c = col[e];
        if (lane < NV) {
            ushort4 g0 = *(const ushort4*)&g[(size_t)c * F + lane * 4];
            a0 += b2f(g0.x); a1 += b2f(g0.y); a2 += b2f(g0.z); a3 += b2f(g0.w);
        }
    }
    if (lane < NV) {
        const float di = dinv[v];
        float4 r;
        r.x = a0 * di + b[lane * 4 + 0];
        r.y = a1 * di + b[lane * 4 + 1];
        r.z = a2 * di + b[lane * 4 + 2];
        r.w = a3 * di + b[lane * 4 + 3];
        if (RELU) {
            r.x = fmaxf(r.x, 0.f); r.y = fmaxf(r.y, 0.f);
            r.z = fmaxf(r.z, 0.f); r.w = fmaxf(r.w, 0.f);
        }
        *(float4*)&out[(size_t)v * F + lane * 4] = r;
    }
}

extern "C" void kernel_launch(void* const* d_in, const int* in_sizes, int n_in,
                              void* d_out, int out_size, void* d_ws, size_t ws_size,
                              hipStream_t stream) {
    const float* x    = (const float*)d_in[0];
    const int*   ei   = (const int*)d_in[1];
    const float* W1   = (const float*)d_in[4];
    const float* b1   = (const float*)d_in[5];
    const float* Wsl  = (const float*)d_in[6];
    const float* bsl  = (const float*)d_in[7];
    const float* Wout = (const float*)d_in[8];
    const float* bout = (const float*)d_in[9];

    const int n = in_sizes[0] / 96;  // 50000
    const int E = in_sizes[1] / 2;   // 800000
    const int* src = ei;
    const int* dst = ei + E;

    // ws: degi[n] | row_start[n+1] | cnt[n] | col[E] (int) | dinv[n] (f32) | g[n*96] (bf16)
    int*     degi      = (int*)d_ws;
    int*     row_start = degi + n;
    int*     cnt       = row_start + n + 1;
    int*     col       = cnt + n;
    float*   dinv      = (float*)(col + E);
    ushortT* g         = (ushortT*)(dinv + n);

    float* out  = (float*)d_out;          // [n,64]
    float* hseg = out + (size_t)n * 64;   // h1 base; 5 segments of n*96

    const int nthr  = 256;
    const int gE    = (E + nthr - 1) / nthr;
    const int gAgg  = (n + 3) / 4;        // 4 waves/block, 1 node/wave
    const int gT64  = (n + 63) / 64;

    // CSR build (same work every call; graph-capture-safe)
    hipMemsetAsync(degi, 0, (size_t)n * sizeof(int), stream);
    count_kernel<<<gE, nthr, 0, stream>>>(dst, degi, E);
    scan_kernel<<<1, 1024, 0, stream>>>(degi, row_start, dinv, n);
    hipMemsetAsync(cnt, 0, (size_t)n * sizeof(int), stream);
    fill_kernel<<<gE, nthr, 0, stream>>>(src, dst, row_start, cnt, col, E);

    // layer 1
    gemm96_v2<<<gT64, 384, 0, stream>>>(x, W1, dinv, g, n);
    agg_csr<96, true><<<gAgg, nthr, 0, stream>>>(row_start, col, g, dinv, b1, hseg, n);

    // hidden layers 2..5
    for (int l = 0; l < 4; ++l) {
        const float* hin = hseg + (size_t)l * (size_t)n * 96;
        float* hnext     = hseg + (size_t)(l + 1) * (size_t)n * 96;
        gemm96_v2<<<gT64, 384, 0, stream>>>(hin, Wsl + (size_t)l * 96 * 96, dinv, g, n);
        agg_csr<96, true><<<gAgg, nthr, 0, stream>>>(row_start, col, g, dinv,
                                                     bsl + (size_t)l * 96, hnext, n);
    }

    // output layer
    gemm_out_v2<<<gT64, 256, 0, stream>>>(hseg, Wout, dinv, g, n);
    agg_csr<64, false><<<gAgg, nthr, 0, stream>>>(row_start, col, g, dinv, bout, out, n);
}

// Round 6
// 657.729 us; speedup vs baseline: 3.2239x; 1.1972x over previous
//
#include <hip/hip_runtime.h>

// JKNet (6-layer GCN + JK concat) on MI355X — R6:
//   * hierarchical CSR scan (R5's single-block scan was 110 us, 0.14% occupancy)
//   * fill uses atomicSub on degi (no cnt array / no 2nd memset); row_start[n]=E static
//   * agg: dual-half waves (even/odd edges), 2 edges/half/iter, shfl-combine
// Per layer: g = bf16((X@W)*dinv[row]); h[v] = act((sum_{N(v)} g[s] + g[v])*dinv[v] + b).

typedef unsigned short ushortT;

__device__ __forceinline__ ushortT f2b(float f) {
    union { float f; unsigned int u; } v;
    v.f = f;
    unsigned int lsb = (v.u >> 16) & 1u;
    v.u += 0x7fffu + lsb;  // RNE
    return (ushortT)(v.u >> 16);
}
__device__ __forceinline__ float b2f(ushortT u) {
    union { float f; unsigned int u; } v;
    v.u = ((unsigned int)u) << 16;
    return v.f;
}

// ---- CSR build -------------------------------------------------------------
__global__ void count_kernel(const int* __restrict__ dst, int* __restrict__ degi, int E) {
    int e = blockIdx.x * blockDim.x + threadIdx.x;
    if (e < E) atomicAdd(&degi[dst[e]], 1);
}

// Stage 1: per-block (256 elems) exclusive scan into row_start; block sum -> partials.
__global__ void scan1(const int* __restrict__ degi, int* __restrict__ row_start,
                      int* __restrict__ partials, int n) {
    __shared__ int tmp[256];
    const int t = threadIdx.x;
    const int i = blockIdx.x * 256 + t;
    int val = (i < n) ? degi[i] : 0;
    tmp[t] = val;
    __syncthreads();
    for (int off = 1; off < 256; off <<= 1) {
        int v = (t >= off) ? tmp[t - off] : 0;
        __syncthreads();
        tmp[t] += v;
        __syncthreads();
    }
    if (i < n) row_start[i] = tmp[t] - val;          // exclusive (block-local)
    if (t == 255) partials[blockIdx.x] = tmp[255];   // block total
}

// Stage 2: single block scans nb partials (nb <= 256) into exclusive offsets.
__global__ void scan2(int* __restrict__ partials, int nb) {
    __shared__ int tmp[256];
    const int t = threadIdx.x;
    int val = (t < nb) ? partials[t] : 0;
    tmp[t] = val;
    __syncthreads();
    for (int off = 1; off < 256; off <<= 1) {
        int v = (t >= off) ? tmp[t - off] : 0;
        __syncthreads();
        tmp[t] += v;
        __syncthreads();
    }
    if (t < nb) partials[t] = tmp[t] - val;          // exclusive
}

// Stage 3: add block offsets; emit dinv; write row_start[n]=E (known statically).
__global__ void scan3(const int* __restrict__ degi, int* __restrict__ row_start,
                      const int* __restrict__ partials, float* __restrict__ dinv,
                      int n, int E) {
    const int i = blockIdx.x * 256 + threadIdx.x;
    if (i < n) {
        row_start[i] += partials[blockIdx.x];
        dinv[i] = rsqrtf((float)degi[i] + 1.0f);
    }
    if (i == 0) row_start[n] = E;
}

// fill: pos = row_start[d] + (--degi[d]); destroys degi (dinv already computed).
__global__ void fill_kernel(const int* __restrict__ src, const int* __restrict__ dst,
                            const int* __restrict__ row_start, int* __restrict__ degi,
                            int* __restrict__ col, int E) {
    int e = blockIdx.x * blockDim.x + threadIdx.x;
    if (e < E) {
        int d = dst[e];
        int pos = row_start[d] + atomicSub(&degi[d], 1) - 1;
        col[pos] = src[e];
    }
}

// ---- GEMM [n,96]x[96,96] -> g(bf16) = (X@W)*dinv[row]. Tile 64x96, 384 thr, 4x4/thr.
__global__ __launch_bounds__(384) void gemm96_v2(const float* __restrict__ X,
                                                 const float* __restrict__ W,
                                                 const float* __restrict__ dinv,
                                                 ushortT* __restrict__ g, int n) {
    __shared__ float Wl[96 * 96];
    __shared__ float Xl[32][64];
    const int tid = threadIdx.x;
    const int cg = tid % 24;
    const int rg = tid / 24;
    const int row_base = blockIdx.x * 64;
    for (int i = tid * 4; i < 96 * 96; i += 384 * 4)
        *(float4*)&Wl[i] = *(const float4*)&W[i];
    float acc[4][4] = {};
    for (int s = 0; s < 3; ++s) {
        __syncthreads();
        for (int i = tid; i < 512; i += 384) {
            int r = i >> 3, kg = i & 7;
            int grow = min(row_base + r, n - 1);
            float4 vx = *(const float4*)&X[(size_t)grow * 96 + s * 32 + kg * 4];
            Xl[kg * 4 + 0][r] = vx.x;
            Xl[kg * 4 + 1][r] = vx.y;
            Xl[kg * 4 + 2][r] = vx.z;
            Xl[kg * 4 + 3][r] = vx.w;
        }
        __syncthreads();
#pragma unroll
        for (int kk = 0; kk < 32; ++kk) {
            float4 a = *(float4*)&Xl[kk][rg * 4];
            float4 b = *(float4*)&Wl[(s * 32 + kk) * 96 + cg * 4];
            const float av[4] = {a.x, a.y, a.z, a.w};
            const float bv[4] = {b.x, b.y, b.z, b.w};
#pragma unroll
            for (int i = 0; i < 4; ++i)
#pragma unroll
                for (int j = 0; j < 4; ++j) acc[i][j] += av[i] * bv[j];
        }
    }
#pragma unroll
    for (int i = 0; i < 4; ++i) {
        int row = row_base + rg * 4 + i;
        if (row < n) {
            float di = dinv[row];
            ushort4 o;
            o.x = f2b(acc[i][0] * di);
            o.y = f2b(acc[i][1] * di);
            o.z = f2b(acc[i][2] * di);
            o.w = f2b(acc[i][3] * di);
            *(ushort4*)&g[(size_t)row * 96 + cg * 4] = o;
        }
    }
}

// ---- GEMM [n,480]x[480,64] -> g(bf16). Tile 64x64, 256 thr, 4x4/thr.
__global__ __launch_bounds__(256) void gemm_out_v2(const float* __restrict__ hcat,
                                                   const float* __restrict__ W,
                                                   const float* __restrict__ dinv,
                                                   ushortT* __restrict__ g, int n) {
    __shared__ float Wl[32 * 64];
    __shared__ float Xl[32][64];
    const int tid = threadIdx.x;
    const int cg = tid & 15;
    const int rg = tid >> 4;
    const int row_base = blockIdx.x * 64;
    float acc[4][4] = {};
    for (int s = 0; s < 15; ++s) {
        const float* hl = hcat + (size_t)(s / 3) * (size_t)n * 96;
        const int off = (s % 3) * 32;
        __syncthreads();
        for (int i = tid * 4; i < 32 * 64; i += 256 * 4)
            *(float4*)&Wl[i] = *(const float4*)&W[s * 32 * 64 + i];
        for (int i = tid; i < 512; i += 256) {
            int r = i >> 3, kg = i & 7;
            int grow = min(row_base + r, n - 1);
            float4 vx = *(const float4*)&hl[(size_t)grow * 96 + off + kg * 4];
            Xl[kg * 4 + 0][r] = vx.x;
            Xl[kg * 4 + 1][r] = vx.y;
            Xl[kg * 4 + 2][r] = vx.z;
            Xl[kg * 4 + 3][r] = vx.w;
        }
        __syncthreads();
#pragma unroll
        for (int kk = 0; kk < 32; ++kk) {
            float4 a = *(float4*)&Xl[kk][rg * 4];
            float4 b = *(float4*)&Wl[kk * 64 + cg * 4];
            const float av[4] = {a.x, a.y, a.z, a.w};
            const float bv[4] = {b.x, b.y, b.z, b.w};
#pragma unroll
            for (int i = 0; i < 4; ++i)
#pragma unroll
                for (int j = 0; j < 4; ++j) acc[i][j] += av[i] * bv[j];
        }
    }
#pragma unroll
    for (int i = 0; i < 4; ++i) {
        int row = row_base + rg * 4 + i;
        if (row < n) {
            float di = dinv[row];
            ushort4 o;
            o.x = f2b(acc[i][0] * di);
            o.y = f2b(acc[i][1] * di);
            o.z = f2b(acc[i][2] * di);
            o.w = f2b(acc[i][3] * di);
            *(ushort4*)&g[(size_t)row * 64 + cg * 4] = o;
        }
    }
}

// ---- CSR gather-aggregate: dual-half wave, 2 edges/half/iter ---------------
// One wave per node. Half-wave h (lanes h*32..h*32+31) handles edges e0+h, e0+h+2, ...
// lanes (lane&31) < F/4 hold ushort4 feature chunks. Halves combined via shfl_xor(32).
template <int F, bool RELU>
__global__ void agg_csr(const int* __restrict__ row_start, const int* __restrict__ col,
                        const ushortT* __restrict__ g, const float* __restrict__ dinv,
                        const float* __restrict__ b, float* __restrict__ out, int n) {
    constexpr int NV = F / 4;
    const int lane = threadIdx.x & 63;
    const int half = lane >> 5;
    const int l32 = lane & 31;
    const int v = blockIdx.x * (blockDim.x >> 6) + (threadIdx.x >> 6);
    if (v >= n) return;
    const int e0 = row_start[v];
    const int e1 = row_start[v + 1];
    const bool act = (l32 < NV);
    float a0 = 0.f, a1 = 0.f, a2 = 0.f, a3 = 0.f;
    if (half == 0 && act) {  // self loop
        ushort4 s = *(const ushort4*)&g[(size_t)v * F + l32 * 4];
        a0 = b2f(s.x); a1 = b2f(s.y); a2 = b2f(s.z); a3 = b2f(s.w);
    }
    int e = e0 + half;
    for (; e + 2 < e1; e += 4) {  // 2 edges per half per iter (4 total in flight)
        int c0 = col[e], c1 = col[e + 2];
        if (act) {
            ushort4 g0 = *(const ushort4*)&g[(size_t)c0 * F + l32 * 4];
            ushort4 g1 = *(const ushort4*)&g[(size_t)c1 * F + l32 * 4];
            a0 += b2f(g0.x) + b2f(g1.x);
            a1 += b2f(g0.y) + b2f(g1.y);
            a2 += b2f(g0.z) + b2f(g1.z);
            a3 += b2f(g0.w) + b2f(g1.w);
        }
    }
    for (; e < e1; e += 2) {
        int c = col[e];
        if (act) {
            ushort4 g0 = *(const ushort4*)&g[(size_t)c * F + l32 * 4];
            a0 += b2f(g0.x); a1 += b2f(g0.y); a2 += b2f(g0.z); a3 += b2f(g0.w);
        }
    }
    // combine odd/even halves
    a0 += __shfl_xor(a0, 32);
    a1 += __shfl_xor(a1, 32);
    a2 += __shfl_xor(a2, 32);
    a3 += __shfl_xor(a3, 32);
    if (half == 0 && act) {
        const float di = dinv[v];
        float4 r;
        r.x = a0 * di + b[l32 * 4 + 0];
        r.y = a1 * di + b[l32 * 4 + 1];
        r.z = a2 * di + b[l32 * 4 + 2];
        r.w = a3 * di + b[l32 * 4 + 3];
        if (RELU) {
            r.x = fmaxf(r.x, 0.f); r.y = fmaxf(r.y, 0.f);
            r.z = fmaxf(r.z, 0.f); r.w = fmaxf(r.w, 0.f);
        }
        *(float4*)&out[(size_t)v * F + l32 * 4] = r;
    }
}

extern "C" void kernel_launch(void* const* d_in, const int* in_sizes, int n_in,
                              void* d_out, int out_size, void* d_ws, size_t ws_size,
                              hipStream_t stream) {
    const float* x    = (const float*)d_in[0];
    const int*   ei   = (const int*)d_in[1];
    const float* W1   = (const float*)d_in[4];
    const float* b1   = (const float*)d_in[5];
    const float* Wsl  = (const float*)d_in[6];
    const float* bsl  = (const float*)d_in[7];
    const float* Wout = (const float*)d_in[8];
    const float* bout = (const float*)d_in[9];

    const int n = in_sizes[0] / 96;  // 50000
    const int E = in_sizes[1] / 2;   // 800000
    const int* src = ei;
    const int* dst = ei + E;

    // ws: degi[n] | row_start[n+1] | partials[256] | col[E] (int) | dinv[n] (f32) | g[n*96] (bf16)
    int*     degi      = (int*)d_ws;
    int*     row_start = degi + n;
    int*     partials  = row_start + n + 1;
    int*     col       = partials + 256;
    float*   dinv      = (float*)(col + E);
    ushortT* g         = (ushortT*)(dinv + n);

    float* out  = (float*)d_out;          // [n,64]
    float* hseg = out + (size_t)n * 64;   // h1 base; 5 segments of n*96

    const int nthr = 256;
    const int gE   = (E + nthr - 1) / nthr;
    const int gAgg = (n + 3) / 4;         // 4 waves/block, 1 node/wave
    const int gT64 = (n + 63) / 64;
    const int nb   = (n + 255) / 256;     // 196 scan blocks

    // CSR build (same work every call; graph-capture-safe)
    hipMemsetAsync(degi, 0, (size_t)n * sizeof(int), stream);
    count_kernel<<<gE, nthr, 0, stream>>>(dst, degi, E);
    scan1<<<nb, 256, 0, stream>>>(degi, row_start, partials, n);
    scan2<<<1, 256, 0, stream>>>(partials, nb);
    scan3<<<nb, 256, 0, stream>>>(degi, row_start, partials, dinv, n, E);
    fill_kernel<<<gE, nthr, 0, stream>>>(src, dst, row_start, degi, col, E);

    // layer 1
    gemm96_v2<<<gT64, 384, 0, stream>>>(x, W1, dinv, g, n);
    agg_csr<96, true><<<gAgg, nthr, 0, stream>>>(row_start, col, g, dinv, b1, hseg, n);

    // hidden layers 2..5
    for (int l = 0; l < 4; ++l) {
        const float* hin = hseg + (size_t)l * (size_t)n * 96;
        float* hnext     = hseg + (size_t)(l + 1) * (size_t)n * 96;
        gemm96_v2<<<gT64, 384, 0, stream>>>(hin, Wsl + (size_t)l * 96 * 96, dinv, g, n);
        agg_csr<96, true><<<gAgg, nthr, 0, stream>>>(row_start, col, g, dinv,
                                                     bsl + (size_t)l * 96, hnext, n);
    }

    // output layer
    gemm_out_v2<<<gT64, 256, 0, stream>>>(hseg, Wout, dinv, g, n);
    agg_csr<64, false><<<gAgg, nthr, 0, stream>>>(row_start, col, g, dinv, bout, out, n);
}

// Round 7
// 571.899 us; speedup vs baseline: 3.7078x; 1.1501x over previous
//
#include <hip/hip_runtime.h>

// JKNet (6-layer GCN + JK concat) on MI355X — R7: bf16 MFMA GEMMs.
//   * weights pre-transposed+converted to bf16 Wt[c][k] once per call
//   * gemm96/gemm_out use v_mfma_f32_16x16x32_bf16, LDS tiles padded to 104 bf16/row
//   * agg epilogue also emits bf16 h (hb) as next layer's GEMM input
// Layout facts (learn_hip m89): A[m=lane&15][k=quad*8+j], B[k][n=lane&15] (k=quad*8+j),
// D: col=lane&15, row=quad*4+reg.

typedef unsigned short ushortT;
typedef __attribute__((ext_vector_type(8))) short bf16x8;
typedef __attribute__((ext_vector_type(4))) float f32x4;

__device__ __forceinline__ ushortT f2b(float f) {
    union { float f; unsigned int u; } v;
    v.f = f;
    unsigned int lsb = (v.u >> 16) & 1u;
    v.u += 0x7fffu + lsb;  // RNE
    return (ushortT)(v.u >> 16);
}
__device__ __forceinline__ float b2f(ushortT u) {
    union { float f; unsigned int u; } v;
    v.u = ((unsigned int)u) << 16;
    return v.f;
}

// ---- weight transpose+convert: Wt[c*K+k] = bf16(W[k*C+c]) ------------------
__global__ void tw_kernel(const float* __restrict__ W, ushortT* __restrict__ Wt,
                          int K, int C) {
    int i = blockIdx.x * blockDim.x + threadIdx.x;
    if (i < K * C) {
        int c = i / K, k = i - c * K;
        Wt[i] = f2b(W[(size_t)k * C + c]);
    }
}

// ---- CSR build -------------------------------------------------------------
__global__ void count_kernel(const int* __restrict__ dst, int* __restrict__ degi, int E) {
    int e = blockIdx.x * blockDim.x + threadIdx.x;
    if (e < E) atomicAdd(&degi[dst[e]], 1);
}

__global__ void scan1(const int* __restrict__ degi, int* __restrict__ row_start,
                      int* __restrict__ partials, int n) {
    __shared__ int tmp[256];
    const int t = threadIdx.x;
    const int i = blockIdx.x * 256 + t;
    int val = (i < n) ? degi[i] : 0;
    tmp[t] = val;
    __syncthreads();
    for (int off = 1; off < 256; off <<= 1) {
        int v = (t >= off) ? tmp[t - off] : 0;
        __syncthreads();
        tmp[t] += v;
        __syncthreads();
    }
    if (i < n) row_start[i] = tmp[t] - val;
    if (t == 255) partials[blockIdx.x] = tmp[255];
}

__global__ void scan2(int* __restrict__ partials, int nb) {
    __shared__ int tmp[256];
    const int t = threadIdx.x;
    int val = (t < nb) ? partials[t] : 0;
    tmp[t] = val;
    __syncthreads();
    for (int off = 1; off < 256; off <<= 1) {
        int v = (t >= off) ? tmp[t - off] : 0;
        __syncthreads();
        tmp[t] += v;
        __syncthreads();
    }
    if (t < nb) partials[t] = tmp[t] - val;
}

__global__ void scan3(const int* __restrict__ degi, int* __restrict__ row_start,
                      const int* __restrict__ partials, float* __restrict__ dinv,
                      int n, int E) {
    const int i = blockIdx.x * 256 + threadIdx.x;
    if (i < n) {
        row_start[i] += partials[blockIdx.x];
        dinv[i] = rsqrtf((float)degi[i] + 1.0f);
    }
    if (i == 0) row_start[n] = E;
}

__global__ void fill_kernel(const int* __restrict__ src, const int* __restrict__ dst,
                            const int* __restrict__ row_start, int* __restrict__ degi,
                            int* __restrict__ col, int E) {
    int e = blockIdx.x * blockDim.x + threadIdx.x;
    if (e < E) {
        int d = dst[e];
        int pos = row_start[d] + atomicSub(&degi[d], 1) - 1;
        col[pos] = src[e];
    }
}

// ---- MFMA GEMM [n,96]x[96,96] -> g(bf16) = (X@W)*dinv[row] -----------------
// 64 rows/block, 256 thr = 4 waves, wave = 16-row strip x 96 cols (6 mfma accs).
// TIN = float (convert in staging) or ushortT (bf16 passthrough).
template <typename TIN>
__global__ __launch_bounds__(256) void gemm96_mfma(const TIN* __restrict__ X,
                                                   const ushortT* __restrict__ Wt, // [96][96] c-major
                                                   const float* __restrict__ dinv,
                                                   ushortT* __restrict__ g, int n) {
    __shared__ __attribute__((aligned(16))) ushortT Xl[64][104];
    __shared__ __attribute__((aligned(16))) ushortT Wtl[96][104];
    const int tid = threadIdx.x;
    const int wave = tid >> 6, lane = tid & 63;
    const int quad = lane >> 4, m = lane & 15;
    const int row_base = blockIdx.x * 64;
    // stage W^T (bf16 [c][k] global, contiguous k) -> Wtl
    for (int i = tid; i < 96 * 24; i += 256) {
        int r = i / 24, c4 = (i % 24) * 4;
        *(ushort4*)&Wtl[r][c4] = *(const ushort4*)&Wt[r * 96 + c4];
    }
    // stage X rows (clamped) -> Xl, converting if fp32
    for (int i = tid; i < 64 * 24; i += 256) {
        int r = i / 24, c4 = (i % 24) * 4;
        int grow = min(row_base + r, n - 1);
        if constexpr (sizeof(TIN) == 4) {
            float4 v = *(const float4*)&X[(size_t)grow * 96 + c4];
            ushort4 o = {f2b(v.x), f2b(v.y), f2b(v.z), f2b(v.w)};
            *(ushort4*)&Xl[r][c4] = o;
        } else {
            *(ushort4*)&Xl[r][c4] = *(const ushort4*)&X[(size_t)grow * 96 + c4];
        }
    }
    __syncthreads();
    f32x4 acc[6] = {};
#pragma unroll
    for (int ks = 0; ks < 3; ++ks) {
        bf16x8 a = *(bf16x8*)&Xl[wave * 16 + m][ks * 32 + quad * 8];
#pragma unroll
        for (int ct = 0; ct < 6; ++ct) {
            bf16x8 b = *(bf16x8*)&Wtl[ct * 16 + m][ks * 32 + quad * 8];
            acc[ct] = __builtin_amdgcn_mfma_f32_16x16x32_bf16(a, b, acc[ct], 0, 0, 0);
        }
    }
    // epilogue: D col=lane&15, row=quad*4+reg
    float di[4];
    int rows[4];
#pragma unroll
    for (int r = 0; r < 4; ++r) {
        rows[r] = row_base + wave * 16 + quad * 4 + r;
        di[r] = (rows[r] < n) ? dinv[rows[r]] : 0.f;
    }
#pragma unroll
    for (int ct = 0; ct < 6; ++ct) {
        int colx = ct * 16 + m;
#pragma unroll
        for (int r = 0; r < 4; ++r)
            if (rows[r] < n) g[(size_t)rows[r] * 96 + colx] = f2b(acc[ct][r] * di[r]);
    }
}

// ---- MFMA GEMM [n,480]x[480,64] -> g(bf16). K = 5 JK segs x 96. ------------
__global__ __launch_bounds__(256) void gemm_out_mfma(const float* __restrict__ hcat,
                                                     const ushortT* __restrict__ Wt, // [64][480]
                                                     const float* __restrict__ dinv,
                                                     ushortT* __restrict__ g, int n) {
    __shared__ __attribute__((aligned(16))) ushortT Xl[64][104];
    __shared__ __attribute__((aligned(16))) ushortT Wtl[64][104];
    const int tid = threadIdx.x;
    const int wave = tid >> 6, lane = tid & 63;
    const int quad = lane >> 4, m = lane & 15;
    const int row_base = blockIdx.x * 64;
    f32x4 acc[4] = {};
    for (int seg = 0; seg < 5; ++seg) {
        const float* hl = hcat + (size_t)seg * (size_t)n * 96;
        __syncthreads();  // protect previous tile
        for (int i = tid; i < 64 * 24; i += 256) {
            int r = i / 24, c4 = (i % 24) * 4;
            *(ushort4*)&Wtl[r][c4] = *(const ushort4*)&Wt[r * 480 + seg * 96 + c4];
        }
        for (int i = tid; i < 64 * 24; i += 256) {
            int r = i / 24, c4 = (i % 24) * 4;
            int grow = min(row_base + r, n - 1);
            float4 v = *(const float4*)&hl[(size_t)grow * 96 + c4];
            ushort4 o = {f2b(v.x), f2b(v.y), f2b(v.z), f2b(v.w)};
            *(ushort4*)&Xl[r][c4] = o;
        }
        __syncthreads();
#pragma unroll
        for (int ks = 0; ks < 3; ++ks) {
            bf16x8 a = *(bf16x8*)&Xl[wave * 16 + m][ks * 32 + quad * 8];
#pragma unroll
            for (int ct = 0; ct < 4; ++ct) {
                bf16x8 b = *(bf16x8*)&Wtl[ct * 16 + m][ks * 32 + quad * 8];
                acc[ct] = __builtin_amdgcn_mfma_f32_16x16x32_bf16(a, b, acc[ct], 0, 0, 0);
            }
        }
    }
    float di[4];
    int rows[4];
#pragma unroll
    for (int r = 0; r < 4; ++r) {
        rows[r] = row_base + wave * 16 + quad * 4 + r;
        di[r] = (rows[r] < n) ? dinv[rows[r]] : 0.f;
    }
#pragma unroll
    for (int ct = 0; ct < 4; ++ct) {
        int colx = ct * 16 + m;
#pragma unroll
        for (int r = 0; r < 4; ++r)
            if (rows[r] < n) g[(size_t)rows[r] * 64 + colx] = f2b(acc[ct][r] * di[r]);
    }
}

// ---- CSR gather-aggregate: dual-half wave, 2 edges/half/iter ---------------
// WRITE_BF16: also emit bf16 h (next layer's GEMM input).
template <int F, bool RELU, bool WRITE_BF16>
__global__ void agg_csr(const int* __restrict__ row_start, const int* __restrict__ col,
                        const ushortT* __restrict__ g, const float* __restrict__ dinv,
                        const float* __restrict__ b, float* __restrict__ out,
                        ushortT* __restrict__ hb, int n) {
    constexpr int NV = F / 4;
    const int lane = threadIdx.x & 63;
    const int half = lane >> 5;
    const int l32 = lane & 31;
    const int v = blockIdx.x * (blockDim.x >> 6) + (threadIdx.x >> 6);
    if (v >= n) return;
    const int e0 = row_start[v];
    const int e1 = row_start[v + 1];
    const bool act = (l32 < NV);
    float a0 = 0.f, a1 = 0.f, a2 = 0.f, a3 = 0.f;
    if (half == 0 && act) {  // self loop
        ushort4 s = *(const ushort4*)&g[(size_t)v * F + l32 * 4];
        a0 = b2f(s.x); a1 = b2f(s.y); a2 = b2f(s.z); a3 = b2f(s.w);
    }
    int e = e0 + half;
    for (; e + 2 < e1; e += 4) {
        int c0 = col[e], c1 = col[e + 2];
        if (act) {
            ushort4 g0 = *(const ushort4*)&g[(size_t)c0 * F + l32 * 4];
            ushort4 g1 = *(const ushort4*)&g[(size_t)c1 * F + l32 * 4];
            a0 += b2f(g0.x) + b2f(g1.x);
            a1 += b2f(g0.y) + b2f(g1.y);
            a2 += b2f(g0.z) + b2f(g1.z);
            a3 += b2f(g0.w) + b2f(g1.w);
        }
    }
    for (; e < e1; e += 2) {
        int c = col[e];
        if (act) {
            ushort4 g0 = *(const ushort4*)&g[(size_t)c * F + l32 * 4];
            a0 += b2f(g0.x); a1 += b2f(g0.y); a2 += b2f(g0.z); a3 += b2f(g0.w);
        }
    }
    a0 += __shfl_xor(a0, 32);
    a1 += __shfl_xor(a1, 32);
    a2 += __shfl_xor(a2, 32);
    a3 += __shfl_xor(a3, 32);
    if (half == 0 && act) {
        const float di = dinv[v];
        float4 r;
        r.x = a0 * di + b[l32 * 4 + 0];
        r.y = a1 * di + b[l32 * 4 + 1];
        r.z = a2 * di + b[l32 * 4 + 2];
        r.w = a3 * di + b[l32 * 4 + 3];
        if (RELU) {
            r.x = fmaxf(r.x, 0.f); r.y = fmaxf(r.y, 0.f);
            r.z = fmaxf(r.z, 0.f); r.w = fmaxf(r.w, 0.f);
        }
        *(float4*)&out[(size_t)v * F + l32 * 4] = r;
        if (WRITE_BF16) {
            ushort4 o = {f2b(r.x), f2b(r.y), f2b(r.z), f2b(r.w)};
            *(ushort4*)&hb[(size_t)v * F + l32 * 4] = o;
        }
    }
}

extern "C" void kernel_launch(void* const* d_in, const int* in_sizes, int n_in,
                              void* d_out, int out_size, void* d_ws, size_t ws_size,
                              hipStream_t stream) {
    const float* x    = (const float*)d_in[0];
    const int*   ei   = (const int*)d_in[1];
    const float* W1   = (const float*)d_in[4];
    const float* b1   = (const float*)d_in[5];
    const float* Wsl  = (const float*)d_in[6];
    const float* bsl  = (const float*)d_in[7];
    const float* Wout = (const float*)d_in[8];
    const float* bout = (const float*)d_in[9];

    const int n = in_sizes[0] / 96;  // 50000
    const int E = in_sizes[1] / 2;   // 800000
    const int* src = ei;
    const int* dst = ei + E;

    // ws: degi[n] row_start[n+1] partials[256] col[E] (int) | dinv[n] (f32)
    //     | g[n*96] hb[n*96] (bf16) | wt1[96*96] wts[4*96*96] wto[64*480] (bf16)
    int*     degi      = (int*)d_ws;
    int*     row_start = degi + n;
    int*     partials  = row_start + n + 1;
    int*     col       = partials + 256;
    float*   dinv      = (float*)(col + E);
    ushortT* g         = (ushortT*)(dinv + n);
    ushortT* hb        = g + (size_t)n * 96;
    ushortT* wt1       = hb + (size_t)n * 96;
    ushortT* wts       = wt1 + 96 * 96;
    ushortT* wto       = wts + 4 * 96 * 96;

    float* out  = (float*)d_out;          // [n,64]
    float* hseg = out + (size_t)n * 64;   // h1 base; 5 segments of n*96

    const int nthr = 256;
    const int gE   = (E + nthr - 1) / nthr;
    const int gAgg = (n + 3) / 4;
    const int gT64 = (n + 63) / 64;
    const int nb   = (n + 255) / 256;

    // weight transpose+convert (bf16, c-major)
    tw_kernel<<<(96 * 96 + 255) / 256, 256, 0, stream>>>(W1, wt1, 96, 96);
    for (int l = 0; l < 4; ++l)
        tw_kernel<<<(96 * 96 + 255) / 256, 256, 0, stream>>>(
            Wsl + (size_t)l * 96 * 96, wts + (size_t)l * 96 * 96, 96, 96);
    tw_kernel<<<(480 * 64 + 255) / 256, 256, 0, stream>>>(Wout, wto, 480, 64);

    // CSR build
    hipMemsetAsync(degi, 0, (size_t)n * sizeof(int), stream);
    count_kernel<<<gE, nthr, 0, stream>>>(dst, degi, E);
    scan1<<<nb, 256, 0, stream>>>(degi, row_start, partials, n);
    scan2<<<1, 256, 0, stream>>>(partials, nb);
    scan3<<<nb, 256, 0, stream>>>(degi, row_start, partials, dinv, n, E);
    fill_kernel<<<gE, nthr, 0, stream>>>(src, dst, row_start, degi, col, E);

    // layer 1: x(fp32) -> g -> h1 (+hb)
    gemm96_mfma<float><<<gT64, 256, 0, stream>>>(x, wt1, dinv, g, n);
    agg_csr<96, true, true><<<gAgg, nthr, 0, stream>>>(row_start, col, g, dinv, b1,
                                                       hseg, hb, n);

    // hidden layers 2..5: hb(bf16) -> g -> h_{l+1} (+hb)
    for (int l = 0; l < 4; ++l) {
        float* hnext = hseg + (size_t)(l + 1) * (size_t)n * 96;
        gemm96_mfma<ushortT><<<gT64, 256, 0, stream>>>(hb, wts + (size_t)l * 96 * 96,
                                                       dinv, g, n);
        agg_csr<96, true, true><<<gAgg, nthr, 0, stream>>>(row_start, col, g, dinv,
                                                           bsl + (size_t)l * 96, hnext, hb, n);
    }

    // output layer: JK concat (fp32 h in d_out) -> out[n,64]
    gemm_out_mfma<<<gT64, 256, 0, stream>>>(hseg, wto, dinv, g, n);
    agg_csr<64, false, false><<<gAgg, nthr, 0, stream>>>(row_start, col, g, dinv, bout,
                                                         out, nullptr, n);
}